// Round 4
// baseline (672.294 us; speedup 1.0000x reference)
//
#include <hip/hip_runtime.h>

#define IMG   256
#define NPIX  65536          // 256*256
#define PH    63             // patches per side
#define NNODE 3969           // PH*PH
#define SN    4000           // padded node stride (mult of 32, 16B-aligned rows)
#define HID   64
#define GH    128
#define BATCH 4

typedef __attribute__((ext_vector_type(8))) short short8;
typedef __attribute__((ext_vector_type(4))) float float4v;
typedef unsigned short ushort_t;

__device__ inline ushort_t f2bf(float f) {
    union { float f; unsigned u; } v; v.f = f;
    unsigned r = v.u + 0x7FFF + ((v.u >> 16) & 1);   // RNE
    return (ushort_t)(r >> 16);
}

// ---------------------------------------------------------------------------
// sup1T[b][g][n] = sum_pix patch[n][pix] * w3[pix][g]   (bf16 out, n-pad zeroed)
// ---------------------------------------------------------------------------
__global__ __launch_bounds__(256) void k_sup1(const float* __restrict__ in,
                                              const float* __restrict__ w3,
                                              ushort_t* __restrict__ sup1T) {
    int b = blockIdx.z;
    int g = blockIdx.y * 8 + (threadIdx.x >> 5);
    int n = blockIdx.x * 32 + (threadIdx.x & 31);
    ushort_t* dst = sup1T + (size_t)b * GH * SN + (size_t)g * SN + n;
    if (n >= NNODE) { *dst = 0; return; }
    int py = n / PH, px = n - py * PH;
    const float* base = in + (size_t)b * NPIX + (py * 4) * IMG + px * 4;
    float acc = 0.f;
#pragma unroll
    for (int i = 0; i < 8; ++i)
#pragma unroll
        for (int j = 0; j < 8; ++j)
            acc += base[i * IMG + j] * w3[(i * 8 + j) * GH + g];
    *dst = f2bf(acc);
}

// ---------------------------------------------------------------------------
// FUSED cvt+GEMM: C[g][n] += sum_k sup1T[g][k] * bf16(adj[n][k])
// B-operand staged by converting fp32 adj tiles inline (scalar dword loads —
// adj rows are 3969 floats, 4B-aligned only). Each converted 16B group is
// written once to LDS AND once to adjb global (exactly-once coverage across
// the grid: 32 node-tiles x 4 ks-tiles partition [N) x [SN); pad cols zeroed,
// rows >= NNODE guarded). gemm<64> consumes adjb later, bitwise-identical to
// the old separate k_cvt_adj.
// ---------------------------------------------------------------------------
__global__ __launch_bounds__(256) void k_gemm_cvt128(const float* __restrict__ adj,
                                                     ushort_t* __restrict__ adjb,
                                                     const ushort_t* __restrict__ supT,
                                                     float* __restrict__ C) {
    const int b = blockIdx.z, ks = blockIdx.y;
    const int node0 = blockIdx.x * 128;
    const int t = threadIdx.x;
    const int lane = t & 63, w = t >> 6;
    const int l15 = lane & 15, q = lane >> 4;
    const int wm0 = (w & 1) * 64;
    const int wn0 = (w >> 1) * 64;

    __shared__ ushort_t Als[128][72];
    __shared__ ushort_t Bls[128][72];

    const int k0c = ks * 992;
    const int kend = (ks == 3) ? NNODE : k0c + 992;
    const int kiters = (kend - k0c + 31) >> 5;       // 31 (ks<3) or 32 (ks=3)
    const int npairs = (kiters + 1) >> 1;            // 16

    const ushort_t* Ab = supT + (size_t)b * 128 * SN;
    const float*    Aj = adj  + (size_t)b * NNODE * NNODE;
    ushort_t*       Jb = adjb + (size_t)b * NNODE * SN;
    float* Cb = C + (size_t)b * 128 * SN;

    float4v acc[4][4];
#pragma unroll
    for (int i = 0; i < 4; ++i)
#pragma unroll
        for (int j = 0; j < 4; ++j)
#pragma unroll
            for (int r = 0; r < 4; ++r) acc[i][j][r] = 0.f;

    auto stageB = [&](int kb, int loff) {
#pragma unroll
        for (int i = 0; i < 2; ++i) {
            int idx = t + i * 256;
            int r = idx >> 2, s = idx & 3;
            int row = node0 + r;
            int col = kb + s * 8;
            unsigned pk[4] = {0u, 0u, 0u, 0u};
            if (row < NNODE) {
                const float* src = Aj + (size_t)row * NNODE + col;
                if (col + 8 <= NNODE) {
#pragma unroll
                    for (int h = 0; h < 4; ++h)
                        pk[h] = (unsigned)f2bf(src[2 * h]) |
                                ((unsigned)f2bf(src[2 * h + 1]) << 16);
                } else {
#pragma unroll
                    for (int h = 0; h < 4; ++h) {
                        float f0 = (col + 2 * h     < NNODE) ? src[2 * h]     : 0.f;
                        float f1 = (col + 2 * h + 1 < NNODE) ? src[2 * h + 1] : 0.f;
                        pk[h] = (unsigned)f2bf(f0) | ((unsigned)f2bf(f1) << 16);
                    }
                }
                *(uint4*)&Jb[(size_t)row * SN + col] = *(uint4*)pk;
            }
            *(uint4*)&Bls[r][loff + s * 8] = *(uint4*)pk;
        }
    };

    for (int kp = 0; kp < npairs; ++kp) {
        const int kb0 = k0c + kp * 64;
        const bool has2 = (kp * 2 + 1 < kiters);     // wave-uniform
        // A: bf16 from sup1T
#pragma unroll
        for (int i = 0; i < 2; ++i) {
            int idx = t + i * 256;
            int r = idx >> 2, s = idx & 3;
            *(uint4*)&Als[r][s * 8] =
                *(const uint4*)&Ab[(size_t)r * SN + kb0 + s * 8];
        }
        if (has2) {
#pragma unroll
            for (int i = 0; i < 2; ++i) {
                int idx = t + i * 256;
                int r = idx >> 2, s = idx & 3;
                *(uint4*)&Als[r][32 + s * 8] =
                    *(const uint4*)&Ab[(size_t)r * SN + kb0 + 32 + s * 8];
            }
        }
        // B: convert fp32 adj -> bf16 (LDS + adjb)
        stageB(kb0, 0);
        if (has2) stageB(kb0 + 32, 32);
        __syncthreads();
        {
            short8 af[4], bf[4];
#pragma unroll
            for (int i = 0; i < 4; ++i)
                af[i] = *(const short8*)&Als[wm0 + i * 16 + l15][q * 8];
#pragma unroll
            for (int j = 0; j < 4; ++j)
                bf[j] = *(const short8*)&Bls[wn0 + j * 16 + l15][q * 8];
#pragma unroll
            for (int i = 0; i < 4; ++i)
#pragma unroll
                for (int j = 0; j < 4; ++j)
                    acc[i][j] = __builtin_amdgcn_mfma_f32_16x16x32_bf16(
                        af[i], bf[j], acc[i][j], 0, 0, 0);
        }
        if (has2) {
            short8 af[4], bf[4];
#pragma unroll
            for (int i = 0; i < 4; ++i)
                af[i] = *(const short8*)&Als[wm0 + i * 16 + l15][32 + q * 8];
#pragma unroll
            for (int j = 0; j < 4; ++j)
                bf[j] = *(const short8*)&Bls[wn0 + j * 16 + l15][32 + q * 8];
#pragma unroll
            for (int i = 0; i < 4; ++i)
#pragma unroll
                for (int j = 0; j < 4; ++j)
                    acc[i][j] = __builtin_amdgcn_mfma_f32_16x16x32_bf16(
                        af[i], bf[j], acc[i][j], 0, 0, 0);
        }
        __syncthreads();
    }
#pragma unroll
    for (int i = 0; i < 4; ++i) {
        int gg = wm0 + i * 16 + q * 4;
#pragma unroll
        for (int j = 0; j < 4; ++j) {
            int nn = node0 + wn0 + j * 16 + l15;
            if (nn < NNODE) {
#pragma unroll
                for (int r = 0; r < 4; ++r)
                    unsafeAtomicAdd(&Cb[(size_t)(gg + r) * SN + nn], acc[i][j][r]);
            }
        }
    }
}

// ---------------------------------------------------------------------------
// MFMA GEMM (bf16 B from adjb): C[g][n] += sum_k supT[g][k] * adjb[n][k]
// BK=64: two K=32 chunks staged+computed per barrier pair.
// ---------------------------------------------------------------------------
template <int G>
__global__ __launch_bounds__(256) void k_gemm_mfma(const ushort_t* __restrict__ adjb,
                                                   const ushort_t* __restrict__ supT,
                                                   float* __restrict__ C) {
    constexpr int FN = (G == 128) ? 4 : 2;
    const int b = blockIdx.z, ks = blockIdx.y;
    const int node0 = blockIdx.x * 128;
    const int t = threadIdx.x;
    const int lane = t & 63, w = t >> 6;
    const int l15 = lane & 15, q = lane >> 4;
    const int wm0 = (G == 128) ? (w & 1) * 64 : 0;
    const int wn0 = (G == 128) ? (w >> 1) * 64 : w * 32;

    __shared__ ushort_t Als[G][72];
    __shared__ ushort_t Bls[128][72];

    const int k0c = ks * 992;
    const int kend = (ks == 3) ? NNODE : k0c + 992;
    const int kiters = (kend - k0c + 31) >> 5;       // 31 (ks<3) or 32 (ks=3)
    const int npairs = (kiters + 1) >> 1;            // 16

    const ushort_t* Ab = supT + (size_t)b * G * SN;
    const ushort_t* Bb = adjb + (size_t)b * NNODE * SN;
    float* Cb = C + (size_t)b * G * SN;

    float4v acc[4][FN];
#pragma unroll
    for (int i = 0; i < 4; ++i)
#pragma unroll
        for (int j = 0; j < FN; ++j)
#pragma unroll
            for (int r = 0; r < 4; ++r) acc[i][j][r] = 0.f;

    for (int kp = 0; kp < npairs; ++kp) {
        const int kb0 = k0c + kp * 64;
        const bool has2 = (kp * 2 + 1 < kiters);     // wave-uniform
#pragma unroll
        for (int i = 0; i < G / 64; ++i) {
            int idx = t + i * 256;
            int r = idx >> 2, s = idx & 3;
            *(uint4*)&Als[r][s * 8] =
                *(const uint4*)&Ab[(size_t)r * SN + kb0 + s * 8];
        }
#pragma unroll
        for (int i = 0; i < 2; ++i) {
            int idx = t + i * 256;
            int r = idx >> 2, s = idx & 3;
            *(uint4*)&Bls[r][s * 8] =
                *(const uint4*)&Bb[(size_t)(node0 + r) * SN + kb0 + s * 8];
        }
        if (has2) {
#pragma unroll
            for (int i = 0; i < G / 64; ++i) {
                int idx = t + i * 256;
                int r = idx >> 2, s = idx & 3;
                *(uint4*)&Als[r][32 + s * 8] =
                    *(const uint4*)&Ab[(size_t)r * SN + kb0 + 32 + s * 8];
            }
#pragma unroll
            for (int i = 0; i < 2; ++i) {
                int idx = t + i * 256;
                int r = idx >> 2, s = idx & 3;
                *(uint4*)&Bls[r][32 + s * 8] =
                    *(const uint4*)&Bb[(size_t)(node0 + r) * SN + kb0 + 32 + s * 8];
            }
        }
        __syncthreads();
        {
            short8 af[4], bf[FN];
#pragma unroll
            for (int i = 0; i < 4; ++i)
                af[i] = *(const short8*)&Als[wm0 + i * 16 + l15][q * 8];
#pragma unroll
            for (int j = 0; j < FN; ++j)
                bf[j] = *(const short8*)&Bls[wn0 + j * 16 + l15][q * 8];
#pragma unroll
            for (int i = 0; i < 4; ++i)
#pragma unroll
                for (int j = 0; j < FN; ++j)
                    acc[i][j] = __builtin_amdgcn_mfma_f32_16x16x32_bf16(
                        af[i], bf[j], acc[i][j], 0, 0, 0);
        }
        if (has2) {
            short8 af[4], bf[FN];
#pragma unroll
            for (int i = 0; i < 4; ++i)
                af[i] = *(const short8*)&Als[wm0 + i * 16 + l15][32 + q * 8];
#pragma unroll
            for (int j = 0; j < FN; ++j)
                bf[j] = *(const short8*)&Bls[wn0 + j * 16 + l15][32 + q * 8];
#pragma unroll
            for (int i = 0; i < 4; ++i)
#pragma unroll
                for (int j = 0; j < FN; ++j)
                    acc[i][j] = __builtin_amdgcn_mfma_f32_16x16x32_bf16(
                        af[i], bf[j], acc[i][j], 0, 0, 0);
        }
        __syncthreads();
    }
#pragma unroll
    for (int i = 0; i < 4; ++i) {
        int gg = wm0 + i * 16 + q * 4;
#pragma unroll
        for (int j = 0; j < FN; ++j) {
            int nn = node0 + wn0 + j * 16 + l15;
            if (nn < NNODE) {
#pragma unroll
                for (int r = 0; r < 4; ++r)
                    unsafeAtomicAdd(&Cb[(size_t)(gg + r) * SN + nn], acc[i][j][r]);
            }
        }
    }
}

// ---------------------------------------------------------------------------
// sup2T[b][g][n] = sum_k relu(g1T[k][n] + gb3[k]) * w4[k][g]  (bf16, pad zeroed)
// ---------------------------------------------------------------------------
__global__ __launch_bounds__(256) void k_sup2(const float* __restrict__ g1T,
                                              const float* __restrict__ gb3,
                                              const float* __restrict__ w4,
                                              ushort_t* __restrict__ sup2T) {
    int b = blockIdx.z;
    int g = blockIdx.y * 8 + (threadIdx.x >> 5);
    int n = blockIdx.x * 32 + (threadIdx.x & 31);
    const float* gb = g1T + (size_t)b * GH * SN + n;
    float acc = 0.f;
#pragma unroll 8
    for (int k = 0; k < GH; ++k) {
        float v = fmaxf(gb[(size_t)k * SN] + gb3[k], 0.f);
        acc += v * w4[k * 64 + g];
    }
    sup2T[(size_t)b * 64 * SN + (size_t)g * SN + n] = (n < NNODE) ? f2bf(acc) : 0;
}

// ---------------------------------------------------------------------------
// prepack conv2 weights: cw2 [oc][ic][3][3] fp32 -> W2p [tap][oc][ic] bf16
// ---------------------------------------------------------------------------
__global__ __launch_bounds__(256) void k_prepack(const float* __restrict__ w,
                                                 ushort_t* __restrict__ W2p) {
    int idx = blockIdx.x * 256 + threadIdx.x;   // 9*64*64 = 36864
    if (idx >= 36864) return;
    int tap = idx >> 12, rem = idx & 4095;
    int oc = rem >> 6, ic = rem & 63;
    W2p[idx] = f2bf(w[(oc * 64 + ic) * 9 + tap]);
}

// ---------------------------------------------------------------------------
// conv2f: FUSED conv1 -> conv2(MFMA) -> conv3 channel-contraction.
// ---------------------------------------------------------------------------
__global__ __launch_bounds__(256) void k_conv2f(const float* __restrict__ in,
                                                const float* __restrict__ w1,
                                                const float* __restrict__ b1,
                                                const ushort_t* __restrict__ W2p,
                                                const float* __restrict__ b2,
                                                const float* __restrict__ w3c,
                                                float* __restrict__ U) {
    __shared__ ushort_t Xs[340 * 72];           // 48,960 B
    __shared__ float pre[1088];                 // 4,352 B (overlaid)
    const int b = blockIdx.z;
    const float* inb = in + (size_t)b * NPIX;
    float* Uball = U + (size_t)b * 9 * NPIX;
    const int t = threadIdx.x;
    const int lane = t & 63, w = t >> 6;
    const int l15 = lane & 15, q = lane >> 4;
    const int x0 = blockIdx.x * 32, y0 = blockIdx.y * 8;

    float* sI  = pre;                           // [12][36] input halo^2
    float* ws1 = pre + 432;                     // [576] conv1 weights
    float* bs1 = pre + 1008;                    // [64]  conv1 bias

    for (int idx = t; idx < 432; idx += 256) {
        int yy = idx / 36, xx = idx - yy * 36;
        int gy = y0 + yy - 2, gx = x0 + xx - 2;
        sI[idx] = (gy >= 0 && gy < IMG && gx >= 0 && gx < IMG) ? inb[gy * IMG + gx] : 0.f;
    }
    for (int idx = t; idx < 576; idx += 256) ws1[idx] = w1[idx];
    if (t < 64) bs1[t] = b1[t];
    __syncthreads();

    // conv1 -> Xs: 340 halo px x 64 ch (8 ch per (px,s) work item)
    for (int idx = t; idx < 2720; idx += 256) {
        int hp = idx >> 3, s = idx & 7;
        int hy = hp / 34, hx = hp - hy * 34;
        int gy = y0 + hy - 1, gx = x0 + hx - 1;
        unsigned pk[4] = {0u, 0u, 0u, 0u};
        if (gy >= 0 && gy < IMG && gx >= 0 && gx < IMG) {
            float r[9];
#pragma unroll
            for (int dy = 0; dy < 3; ++dy)
#pragma unroll
                for (int dx = 0; dx < 3; ++dx)
                    r[dy * 3 + dx] = sI[(hy + dy) * 36 + hx + dx];
#pragma unroll
            for (int h = 0; h < 4; ++h) {
                int oc0 = s * 8 + h * 2;
                float a0 = bs1[oc0], a1 = bs1[oc0 + 1];
#pragma unroll
                for (int k = 0; k < 9; ++k) {
                    a0 += r[k] * ws1[oc0 * 9 + k];
                    a1 += r[k] * ws1[(oc0 + 1) * 9 + k];
                }
                a0 = fmaxf(a0, 0.f); a1 = fmaxf(a1, 0.f);
                pk[h] = (unsigned)f2bf(a0) | ((unsigned)f2bf(a1) << 16);
            }
        }
        *(uint4*)&Xs[hp * 72 + s * 8] = *(uint4*)pk;
    }
    __syncthreads();                             // Xs ready; pre phase-A reads done

    // phase B: stage conv3 weights into pre (K-loop reads only Xs/W2p)
    for (int idx = t; idx < 576; idx += 256) pre[idx] = w3c[idx];

    const int wn0 = w * 64;
    int pbase[4];
#pragma unroll
    for (int j = 0; j < 4; ++j) {
        int p = wn0 + j * 16 + l15;
        pbase[j] = (p >> 5) * 34 + (p & 31);
    }

    float4v acc[4][4];
#pragma unroll
    for (int i = 0; i < 4; ++i)
#pragma unroll
        for (int j = 0; j < 4; ++j)
#pragma unroll
            for (int r = 0; r < 4; ++r) acc[i][j][r] = 0.f;

    for (int tap = 0; tap < 9; ++tap) {
        int ky = tap / 3, kx = tap - ky * 3;
        const ushort_t* wp = W2p + tap * 4096;
#pragma unroll
        for (int c = 0; c < 2; ++c) {
            short8 af[4], bf[4];
#pragma unroll
            for (int i = 0; i < 4; ++i)
                af[i] = *(const short8*)&wp[(i * 16 + l15) * 64 + c * 32 + q * 8];
#pragma unroll
            for (int j = 0; j < 4; ++j)
                bf[j] = *(const short8*)&Xs[(pbase[j] + ky * 34 + kx) * 72 + c * 32 + q * 8];
#pragma unroll
            for (int i = 0; i < 4; ++i)
#pragma unroll
                for (int j = 0; j < 4; ++j)
                    acc[i][j] = __builtin_amdgcn_mfma_f32_16x16x32_bf16(
                        af[i], bf[j], acc[i][j], 0, 0, 0);
        }
    }
    __syncthreads();                             // w3c visible to all threads

    // epilogue: relu(conv2+b2), contract over oc against w3c -> 9 U planes
    float b2r[16];
#pragma unroll
    for (int i = 0; i < 4; ++i)
#pragma unroll
        for (int r = 0; r < 4; ++r) b2r[i * 4 + r] = b2[i * 16 + q * 4 + r];

#pragma unroll
    for (int j = 0; j < 4; ++j) {
        float u[9];
#pragma unroll
        for (int d = 0; d < 9; ++d) u[d] = 0.f;
#pragma unroll
        for (int i = 0; i < 4; ++i)
#pragma unroll
            for (int r = 0; r < 4; ++r) {
                int oc = i * 16 + q * 4 + r;
                float h = fmaxf(acc[i][j][r] + b2r[i * 4 + r], 0.f);
#pragma unroll
                for (int d = 0; d < 9; ++d) u[d] += h * pre[oc * 9 + d];
            }
#pragma unroll
        for (int d = 0; d < 9; ++d) {
            u[d] += __shfl_xor(u[d], 16, 64);
            u[d] += __shfl_xor(u[d], 32, 64);
        }
        int p = wn0 + j * 16 + l15;
        int y = y0 + (p >> 5), x = x0 + (p & 31);
#pragma unroll
        for (int dd = 0; dd < 3; ++dd) {
            int d = q + dd * 4;                 // q0:{0,4,8} q1:{1,5} q2:{2,6} q3:{3,7}
            if (d < 9)
                Uball[(size_t)d * NPIX + (size_t)y * IMG + x] = u[d];
        }
    }
}

// ---------------------------------------------------------------------------
// combine: out = relu( tmp1 + [bc3 + sum_d U_d(p+off(d))] + gather(g2T+gb4)/cnt )
// ---------------------------------------------------------------------------
__global__ __launch_bounds__(256) void k_combine(const float* __restrict__ in,
                                                 const float* __restrict__ proj,
                                                 const float* __restrict__ lamp,
                                                 const float* __restrict__ U,
                                                 const float* __restrict__ bc,
                                                 const float* __restrict__ g2T,
                                                 const float* __restrict__ gb4,
                                                 float* __restrict__ out) {
    int b = blockIdx.z;
    const float* inb = in + (size_t)b * NPIX;
    const float* prb = proj + (size_t)b * NPIX;
    const float* Ub = U + (size_t)b * 9 * NPIX;
    const float* g2b = g2T + (size_t)b * 64 * SN;
    int tx = threadIdx.x & 15, ty = threadIdx.x >> 4;
    int x = blockIdx.x * 16 + tx, y = blockIdx.y * 16 + ty;

    float acc = bc[0];
#pragma unroll
    for (int dy = 0; dy < 3; ++dy) {
        int yy = y + dy - 1;
#pragma unroll
        for (int dx = 0; dx < 3; ++dx) {
            int xx = x + dx - 1;
            if (yy >= 0 && yy < IMG && xx >= 0 && xx < IMG)
                acc += Ub[(size_t)(dy * 3 + dx) * NPIX + (size_t)yy * IMG + xx];
        }
    }

    float iv = inb[y * IMG + x], pv = prb[y * IMG + x];
    float tmp1 = iv + lamp[0] * (pv - iv);

    int pylo = (y >= 4) ? ((y - 4) >> 2) : 0;
    int pyhi = min(62, y >> 2);
    int pxlo = (x >= 4) ? ((x - 4) >> 2) : 0;
    int pxhi = min(62, x >> 2);
    float sum = 0.f;
    int cnt = 0;
    for (int py = pylo; py <= pyhi; ++py)
        for (int px = pxlo; px <= pxhi; ++px) {
            int pix = (y - 4 * py) * 8 + (x - 4 * px);
            sum += g2b[(size_t)pix * SN + (py * PH + px)] + gb4[pix];
            ++cnt;
        }
    float tmp3 = sum / (float)cnt;

    out[(size_t)b * NPIX + y * IMG + x] = fmaxf(tmp1 + acc + tmp3, 0.f);
}

// ---------------------------------------------------------------------------
extern "C" void kernel_launch(void* const* d_in, const int* in_sizes, int n_in,
                              void* d_out, int out_size, void* d_ws, size_t ws_size,
                              hipStream_t stream) {
    const float* input = (const float*)d_in[0];
    const float* proj  = (const float*)d_in[1];
    const float* adj   = (const float*)d_in[2];
    const float* lam   = (const float*)d_in[3];
    const float* cw1   = (const float*)d_in[4];
    const float* cb1   = (const float*)d_in[5];
    const float* cw2   = (const float*)d_in[6];
    const float* cb2   = (const float*)d_in[7];
    const float* cw3   = (const float*)d_in[8];
    const float* cb3   = (const float*)d_in[9];
    const float* gw3   = (const float*)d_in[10];
    const float* gb3   = (const float*)d_in[11];
    const float* gw4   = (const float*)d_in[12];
    const float* gb4   = (const float*)d_in[13];
    float* out = (float*)d_out;

    // ws layout (bytes):
    //   g2T fp32 [4][64][SN]                    @ 0          (4,096,000)
    //   pool @ 4,096,000:
    //     GCN phase: adjb bf16 [4][N][SN]       (127,008,000)  (written by gemm_cvt128)
    //                sup1T bf16 [4][128][SN]    (4,096,000)
    //                g1T  fp32 [4][128][SN]     (8,192,000)
    //                sup2T bf16 [4][64][SN]     (2,048,000)
    //     conv phase (reuses pool, stream-ordered after gemm<64>):
    //                U   fp32 [4][9][NPIX]      (9,437,184)
    //                W2p bf16 [9][64][64]       (73,728)
    char* base = (char*)d_ws;
    float*    g2T   = (float*)base;
    char*     pool  = base + 4096000;
    ushort_t* adjb  = (ushort_t*)pool;
    ushort_t* sup1T = (ushort_t*)(pool + 127008000);
    float*    g1T   = (float*)(pool + 127008000 + 4096000);
    ushort_t* sup2T = (ushort_t*)(pool + 127008000 + 4096000 + 8192000);
    float*    U     = (float*)pool;
    ushort_t* W2p   = (ushort_t*)(pool + 9437184);

    dim3 blk(256);

    hipMemsetAsync(g1T, 0, 8192000, stream);
    hipMemsetAsync(g2T, 0, 4096000, stream);

    // GCN branch (bf16 MFMA); gemm_cvt128 converts adj inline and emits adjb
    k_sup1<<<dim3(125, 16, BATCH), blk, 0, stream>>>(input, gw3, sup1T);
    k_gemm_cvt128<<<dim3(32, 4, BATCH), blk, 0, stream>>>(adj, adjb, sup1T, g1T);
    k_sup2<<<dim3(125, 8, BATCH), blk, 0, stream>>>(g1T, gb3, gw4, sup2T);
    k_gemm_mfma<64><<<dim3(32, 4, BATCH), blk, 0, stream>>>(adjb, sup2T, g2T);

    // CNN branch + combine (pool reuse safe: stream-ordered after gemm<64>)
    k_prepack<<<dim3(144), blk, 0, stream>>>(cw2, W2p);
    k_conv2f<<<dim3(8, 32, BATCH), blk, 0, stream>>>(input, cw1, cb1, W2p, cb2, cw3, U);
    k_combine<<<dim3(16, 16, BATCH), blk, 0, stream>>>(
        input, proj, lam, U, cb3, g2T, gb4, out);
}